// Round 11
// baseline (371.811 us; speedup 1.0000x reference)
//
#include <hip/hip_runtime.h>

#define N_NODES 50000
#define N_EDGES 800000
#define NGRAPH 64
#define OUTDIM 10
#define NEG 0.1f
#define BN_EPS 1e-5f
#define PADN 50048      // N rounded up to 64
#define NB 98           // coarse buckets (dst >> 9)
#define BK_SHIFT 9
#define BK_NODES 512
#define C_EPB 4096
#define C_BLOCKS 196
#define D_CAP 12288

typedef __attribute__((ext_vector_type(8))) _Float16 f16x8;
typedef __attribute__((ext_vector_type(4))) float f32x4;
typedef __attribute__((ext_vector_type(4))) unsigned u32x4;

// f16 helpers
static __device__ __forceinline__ float h2lo(unsigned u){
  return (float)__builtin_bit_cast(_Float16, (unsigned short)(u & 0xFFFFu));
}
static __device__ __forceinline__ float h2hi(unsigned u){
  return (float)__builtin_bit_cast(_Float16, (unsigned short)(u >> 16));
}
static __device__ __forceinline__ unsigned pack2h(float a, float b){
  unsigned short lo = __builtin_bit_cast(unsigned short, (_Float16)a);
  unsigned short hi = __builtin_bit_cast(unsigned short, (_Float16)b);
  return (((unsigned)hi) << 16) | lo;
}
static __device__ __forceinline__ unsigned short f2h(float a){
  return __builtin_bit_cast(unsigned short, (_Float16)a);
}
static __device__ __forceinline__ float h2f(unsigned short s){
  return (float)__builtin_bit_cast(_Float16, s);
}

__device__ __forceinline__ int lb_search(const int* a, int n, int v){
  int lo = 0, hi = n;
  while (lo < hi){ int m = (lo+hi)>>1; if (a[m] < v) lo = m+1; else hi = m; }
  return lo;
}

// ================= CSR build: 2-level counting sort =================
__global__ __launch_bounds__(1024) void histA_kernel(const int* __restrict__ dst,
      int* __restrict__ bucketTotal){
  __shared__ int cnt[NB];
  const int t = threadIdx.x;
  if (t < NB) cnt[t] = 0;
  __syncthreads();
  const int base = blockIdx.x*C_EPB;
  const int nE = min(C_EPB, N_EDGES - base);
  for (int i = t; i < nE; i += 1024)
    atomicAdd(&cnt[dst[base+i] >> BK_SHIFT], 1);
  __syncthreads();
  if (t < NB) atomicAdd(&bucketTotal[t], cnt[t]);
}

__global__ __launch_bounds__(128) void scanB_kernel(const int* __restrict__ bucketTotal,
      int* __restrict__ bucketBase, int* __restrict__ bucketCursor){
  __shared__ int s[128];
  const int t = threadIdx.x;
  int v = (t < NB) ? bucketTotal[t] : 0;
  s[t] = v; __syncthreads();
  for (int off = 1; off < 128; off <<= 1){
    int a = (t >= off) ? s[t-off] : 0;
    __syncthreads();
    s[t] += a;
    __syncthreads();
  }
  int excl = s[t] - v;
  if (t < NB){ bucketBase[t] = excl; bucketCursor[t] = excl; }
  if (t == NB-1) bucketBase[NB] = s[t];
}

__global__ __launch_bounds__(1024) void scatterC_kernel(const int* __restrict__ src,
      const int* __restrict__ dst, int* __restrict__ bucketCursor,
      unsigned* __restrict__ bucketArr){
  __shared__ int cnt[NB];
  __shared__ int gbase[NB];
  __shared__ int scan_s[128];
  __shared__ unsigned sorted[C_EPB];
  const int t = threadIdx.x;
  if (t < NB) cnt[t] = 0;
  __syncthreads();
  const int ebase = blockIdx.x*C_EPB;
  const int nE = min(C_EPB, N_EDGES - ebase);
  unsigned pk[4]; int bk[4], rk[4];
  #pragma unroll
  for (int i = 0; i < 4; i++){
    int idx = t + i*1024;
    bk[i] = -1;
    if (idx < nE){
      int d = dst[ebase+idx];
      int s0 = src[ebase+idx];
      bk[i] = d >> BK_SHIFT;
      pk[i] = (unsigned)s0 | ((unsigned)(d & (BK_NODES-1)) << 16);
      rk[i] = atomicAdd(&cnt[bk[i]], 1);
    }
  }
  __syncthreads();
  int myc = 0;
  if (t < 128){ myc = (t < NB) ? cnt[t] : 0; scan_s[t] = myc; }
  __syncthreads();
  for (int off = 1; off < 128; off <<= 1){
    int a = 0;
    if (t < 128 && t >= off) a = scan_s[t-off];
    __syncthreads();
    if (t < 128) scan_s[t] += a;
    __syncthreads();
  }
  if (t < NB){
    cnt[t] = scan_s[t] - myc;
    gbase[t] = atomicAdd(&bucketCursor[t], myc);
  }
  __syncthreads();
  #pragma unroll
  for (int i = 0; i < 4; i++)
    if (bk[i] >= 0) sorted[cnt[bk[i]] + rk[i]] = pk[i];
  __syncthreads();
  for (int i = t; i < nE; i += 1024){
    int lo = 0, hi = NB;
    while (hi - lo > 1){ int m = (lo+hi)>>1; if (cnt[m] <= i) lo = m; else hi = m; }
    bucketArr[gbase[lo] + (i - cnt[lo])] = sorted[i];
  }
}

__global__ __launch_bounds__(1024) void buildD_kernel(const unsigned* __restrict__ bucketArr,
      const int* __restrict__ bucketBase, int* __restrict__ offsets, int* __restrict__ col){
  __shared__ int cnt[BK_NODES];
  __shared__ unsigned sorted[D_CAP];
  const int b = blockIdx.x, t = threadIdx.x;
  const int bB = bucketBase[b];
  int nE = bucketBase[b+1] - bB;
  if (nE > D_CAP) nE = D_CAP;
  if (t < BK_NODES) cnt[t] = 0;
  __syncthreads();
  unsigned pk[12]; int rk[12];
  #pragma unroll
  for (int i = 0; i < 12; i++){
    int idx = t + i*1024;
    rk[i] = -1;
    if (idx < nE){
      unsigned e = bucketArr[bB + idx];
      pk[i] = e;
      rk[i] = atomicAdd(&cnt[e >> 16], 1);
    }
  }
  __syncthreads();
  int myc = (t < BK_NODES) ? cnt[t] : 0;
  for (int off = 1; off < BK_NODES; off <<= 1){
    int a = 0;
    if (t < BK_NODES && t >= off) a = cnt[t-off];
    __syncthreads();
    if (t < BK_NODES) cnt[t] += a;
    __syncthreads();
  }
  if (t < BK_NODES){
    int excl = cnt[t] - myc;
    int node = b*BK_NODES + t;
    if (node < N_NODES) offsets[node] = bB + excl;
    cnt[t] = excl;
  }
  if (b == NB-1 && t == 0) offsets[N_NODES] = bucketBase[NB];
  __syncthreads();
  #pragma unroll
  for (int i = 0; i < 12; i++)
    if (rk[i] >= 0) sorted[cnt[pk[i] >> 16] + rk[i]] = pk[i] & 0xFFFFu;
  __syncthreads();
  for (int i = t; i < nE; i += 1024) col[bB + i] = (int)sorted[i];
}

// ---------------- x (fp32) -> f16-pair plane ----------------
__global__ __launch_bounds__(256) void convx_kernel(const float* __restrict__ x, unsigned* __restrict__ hn){
  int i = blockIdx.x*256 + threadIdx.x;
  if (i < N_NODES*64){
    float2 v = ((const float2*)x)[i];
    hn[i] = pack2h(v.x, v.y);
  }
}

// ---------------- weight prep: MFMA-fragment-ordered f16 plane ----------------
__global__ __launch_bounds__(256) void convw_kernel(
    const float* __restrict__ w0, const float* __restrict__ w1,
    const float* __restrict__ w2, const float* __restrict__ w3,
    const float* __restrict__ w4, const float* __restrict__ w5,
    const float* __restrict__ w6, const float* __restrict__ w7,
    unsigned short* __restrict__ Wfrag){
  const float* W;
  switch(blockIdx.x){
    case 0: W=w0; break; case 1: W=w1; break; case 2: W=w2; break; case 3: W=w3; break;
    case 4: W=w4; break; case 5: W=w5; break; case 6: W=w6; break; default: W=w7; break;
  }
  unsigned short* o = Wfrag + (size_t)blockIdx.x*16384;
  for (int i = 0; i < 8; i++){
    int f = threadIdx.x*8 + i;
    int l = f & 63, ct = (f>>6) & 7, kb = f>>9;
    __align__(16) unsigned short hh[8];
    #pragma unroll
    for (int j = 0; j < 8; j++){
      int k = kb*32 + (l>>4)*8 + j;
      int n = ct*16 + (l&15);
      hh[j] = f2h(W[(size_t)k*128 + n]);
    }
    *(uint4*)(o + (size_t)f*8) = *(const uint4*)hh;
  }
}

// ---------------- GIN aggregation: paired-row uint2 gather, 16 edges/iter ----------------
// wave per node; half = lane>=32 takes odd edges, li = lane&31 covers u32 pair 2li,2li+1.
__global__ __launch_bounds__(256) void aggregate_kernel(const unsigned* __restrict__ hn,
        const int* __restrict__ offsets, const int* __restrict__ col,
        unsigned* __restrict__ outA){
  int v = (blockIdx.x*256 + threadIdx.x) >> 6;
  const int lane = threadIdx.x & 63;
  const int half = lane >> 5, li = lane & 31;
  if (v >= N_NODES) return;
  int s = __builtin_amdgcn_readfirstlane(offsets[v]);
  int e = __builtin_amdgcn_readfirstlane(offsets[v+1]);
  float a0, a1, a2, a3;
  {  // self term on half 0 only
    uint2 su = (half == 0) ? *(const uint2*)(hn + (size_t)v*64 + li*2)
                           : make_uint2(0u, 0u);
    a0 = h2lo(su.x); a1 = h2hi(su.x); a2 = h2lo(su.y); a3 = h2hi(su.y);
  }
  int j = s;
  for (; j + 16 <= e; j += 16){                // 16 edges = 8 paired loads in flight
    uint2 g[8];
    #pragma unroll
    for (int i = 0; i < 8; i++){
      int u = col[j + 2*i + half];             // wave-half-uniform broadcast
      g[i] = *(const uint2*)(hn + (size_t)u*64 + li*2);
    }
    float s0 = 0.f, s1 = 0.f, s2 = 0.f, s3 = 0.f;
    #pragma unroll
    for (int i = 0; i < 8; i++){
      s0 += h2lo(g[i].x); s1 += h2hi(g[i].x);
      s2 += h2lo(g[i].y); s3 += h2hi(g[i].y);
    }
    a0 += s0; a1 += s1; a2 += s2; a3 += s3;
  }
  for (; j + 4 <= e; j += 4){                  // 4 edges = 2 paired loads
    int u0 = col[j + half];
    int u1 = col[j + 2 + half];
    uint2 g0 = *(const uint2*)(hn + (size_t)u0*64 + li*2);
    uint2 g1 = *(const uint2*)(hn + (size_t)u1*64 + li*2);
    a0 += h2lo(g0.x) + h2lo(g1.x); a1 += h2hi(g0.x) + h2hi(g1.x);
    a2 += h2lo(g0.y) + h2lo(g1.y); a3 += h2hi(g0.y) + h2hi(g1.y);
  }
  for (; j < e; j += 2){                       // tail, masked second half
    if (j + half < e){
      int u = col[j + half];
      uint2 g = *(const uint2*)(hn + (size_t)u*64 + li*2);
      a0 += h2lo(g.x); a1 += h2hi(g.x); a2 += h2lo(g.y); a3 += h2hi(g.y);
    }
  }
  // merge the two halves
  a0 += __shfl_xor(a0, 32, 64);
  a1 += __shfl_xor(a1, 32, 64);
  a2 += __shfl_xor(a2, 32, 64);
  a3 += __shfl_xor(a3, 32, 64);
  if (half == 0){
    uint2 o = make_uint2(pack2h(a0, a1), pack2h(a2, a3));
    *(uint2*)(outA + (size_t)v*64 + li*2) = o;
  }
}

// ---------------- fused MLP: GEMM1+leaky -> LDS -> barrier -> GEMM2+leaky + stats ----
// 1564 blocks x 256 thr = 4 waves: rg = w&1 (16-row group), ch = w>>1 (64-col half).
__global__ __launch_bounds__(256) void mlp_kernel(const unsigned* __restrict__ Ain,
      const unsigned short* __restrict__ WfA, const unsigned short* __restrict__ WfB,
      const float* __restrict__ biasA, const float* __restrict__ biasB,
      unsigned short* __restrict__ raw, float* __restrict__ stats){
  __shared__ unsigned short mid[32*128];      // 8 KB, XOR-swizzled
  const int tid = threadIdx.x;
  const int w = tid >> 6, l = tid & 63, lr = l & 15, lg = l >> 4;
  const int rg = w & 1, ch = w >> 1;
  const int rowA = blockIdx.x*32 + rg*16 + lr;
  const u32x4* ap = (const u32x4*)(Ain + (size_t)rowA*64);
  const f16x8* wpA = (const f16x8*)WfA;
  const f16x8* wpB = (const f16x8*)WfB;
  f32x4 acc[4];

  // GEMM1: 16 rows x 64 cols (col tiles ch*4 .. +4)
  #pragma unroll
  for (int c = 0; c < 4; c++) acc[c] = (f32x4){0.f,0.f,0.f,0.f};
  #pragma unroll
  for (int kb = 0; kb < 4; kb++){
    f16x8 a = __builtin_bit_cast(f16x8, ap[kb*4 + lg]);
    #pragma unroll
    for (int c = 0; c < 4; c++){
      f16x8 wv = wpA[(kb*8 + ch*4 + c)*64 + l];
      acc[c] = __builtin_amdgcn_mfma_f32_16x16x32_f16(a, wv, acc[c], 0, 0, 0);
    }
  }
  #pragma unroll
  for (int c = 0; c < 4; c++){
    int colc = (ch*4 + c)*16 + lr;
    float bv = biasA[colc];
    #pragma unroll
    for (int r = 0; r < 4; r++){
      int row = rg*16 + lg*4 + r;
      float tv = acc[c][r] + bv;
      float o = fmaxf(tv, NEG*tv);
      int off = (row*256 + colc*2) ^ ((row&7)<<4);
      *(unsigned short*)((char*)mid + off) = f2h(o);
    }
  }
  __syncthreads();

  // GEMM2: same 16 rows x 64 cols, K = 128 from mid
  #pragma unroll
  for (int c = 0; c < 4; c++) acc[c] = (f32x4){0.f,0.f,0.f,0.f};
  const int mrow = rg*16 + lr;
  const int mswz = (mrow&7) << 4;
  #pragma unroll
  for (int kb = 0; kb < 4; kb++){
    int boff = (mrow*256 + kb*64 + lg*16) ^ mswz;
    f16x8 a = __builtin_bit_cast(f16x8, *(const u32x4*)((char*)mid + boff));
    #pragma unroll
    for (int c = 0; c < 4; c++){
      f16x8 wv = wpB[(kb*8 + ch*4 + c)*64 + l];
      acc[c] = __builtin_amdgcn_mfma_f32_16x16x32_f16(a, wv, acc[c], 0, 0, 0);
    }
  }
  const int rowO = blockIdx.x*32 + rg*16 + lg*4;
  #pragma unroll
  for (int c = 0; c < 4; c++){
    const int gcol = (ch*4 + c)*16 + lr;
    const float bv = biasB[gcol];
    float s = 0.f, q = 0.f;
    #pragma unroll
    for (int r = 0; r < 4; r++){
      int grow = rowO + r;
      float tv = acc[c][r] + bv;
      float o = fmaxf(tv, NEG*tv);
      if (grow < N_NODES){
        raw[(size_t)grow*128 + gcol] = f2h(o);
        s += o; q += o*o;
      }
    }
    s += __shfl_xor(s, 16, 64); s += __shfl_xor(s, 32, 64);
    q += __shfl_xor(q, 16, 64); q += __shfl_xor(q, 32, 64);
    if (lg == 0){
      float* st = stats + (blockIdx.x & 7)*256;
      atomicAdd(&st[gcol], s);
      atomicAdd(&st[128 + gcol], q);
    }
  }
}

// ---------------- BN finalize + normalize + leaky: raw f16 -> hn f16-pair ----------------
__global__ __launch_bounds__(256) void normalize_kernel(const unsigned* __restrict__ raw,
      unsigned* __restrict__ hn, const float* __restrict__ stats,
      const float* __restrict__ g, const float* __restrict__ b){
  __shared__ float sc_s[128], sh_s[128];
  int t = threadIdx.x;
  if (t < 128){
    float su = 0.f, qu = 0.f;
    #pragma unroll
    for (int s8 = 0; s8 < 8; s8++){ su += stats[s8*256 + t]; qu += stats[s8*256 + 128 + t]; }
    float mu = su*(1.f/N_NODES), var = qu*(1.f/N_NODES) - mu*mu;
    float s = g[t]*rsqrtf(var + BN_EPS);
    sc_s[t] = s; sh_s[t] = b[t] - mu*s;
  }
  __syncthreads();
  const int total = N_NODES*64;
  for (int i = blockIdx.x*256 + threadIdx.x; i < total; i += gridDim.x*256){
    unsigned u = raw[i];
    int c0 = (i & 63)*2;
    float v0 = h2lo(u)*sc_s[c0]   + sh_s[c0];
    float v1 = h2hi(u)*sc_s[c0+1] + sh_s[c0+1];
    v0 = fmaxf(v0, NEG*v0); v1 = fmaxf(v1, NEG*v1);
    hn[i] = pack2h(v0, v1);
  }
}

// ---------------- pooling with fused BN+leaky (layer 4) ----------------
__global__ __launch_bounds__(128) void pool_kernel(const unsigned short* __restrict__ raw,
      const int* __restrict__ batch, const float* __restrict__ stats,
      const float* __restrict__ g, const float* __restrict__ b, float* __restrict__ pooled){
  int gi = blockIdx.x >> 3, part = blockIdx.x & 7;
  int c = threadIdx.x;
  float su = 0.f, qu = 0.f;
  #pragma unroll
  for (int s8 = 0; s8 < 8; s8++){ su += stats[s8*256 + c]; qu += stats[s8*256 + 128 + c]; }
  float mu = su*(1.f/N_NODES), var = qu*(1.f/N_NODES) - mu*mu;
  float sc = g[c]*rsqrtf(var+BN_EPS), sh = b[c] - mu*sc;
  int s0 = lb_search(batch, N_NODES, gi), e0 = lb_search(batch, N_NODES, gi+1);
  int len = e0 - s0;
  int a  = s0 + ((len*part) >> 3);
  int b2 = s0 + ((len*(part+1)) >> 3);
  float acc = 0.f;
  for (int r = a; r < b2; r++){
    float t = h2f(raw[(size_t)r*128 + c])*sc + sh;
    acc += fmaxf(t, NEG*t);
  }
  atomicAdd(&pooled[gi*128 + c], acc);
}

// ---------------- head ----------------
__global__ __launch_bounds__(128) void fc1_kernel(const float* __restrict__ pooled,
      const int* __restrict__ batch, const float* __restrict__ fc1w,
      const float* __restrict__ fc1b, float* __restrict__ z1){
  __shared__ float ps[128];
  __shared__ float invs;
  const int gi = blockIdx.x, t = threadIdx.x;
  if (t == 0){
    int s = lb_search(batch, N_NODES, gi), e = lb_search(batch, N_NODES, gi+1);
    invs = 1.f / fmaxf((float)(e - s), 1.f);
  }
  ps[t] = pooled[gi*128 + t];
  __syncthreads();
  float inv = invs;
  float acc = 0.f;
  #pragma unroll 8
  for (int k = 0; k < 128; k++) acc += ps[k]*fc1w[k*128 + t];
  z1[gi*128 + t] = acc*inv + fc1b[t];
}

__global__ __launch_bounds__(256) void head2_kernel(const float* __restrict__ z1,
      const float* __restrict__ g, const float* __restrict__ b,
      const float* __restrict__ fc2w, const float* __restrict__ fc2b,
      float* __restrict__ out){
  __shared__ float z[64*128];
  __shared__ float sc_s[128], sh_s[128];
  const int t = threadIdx.x;
  for (int i = t; i < 8192; i += 256) z[i] = z1[i];
  __syncthreads();
  if (t < 128){
    float s = 0.f, q = 0.f;
    for (int r = 0; r < 64; r++){ float v = z[r*128 + t]; s += v; q += v*v; }
    float mu = s*(1.f/64.f), var = q*(1.f/64.f) - mu*mu;
    float scv = g[t] * rsqrtf(var + BN_EPS);
    sc_s[t] = scv; sh_s[t] = b[t] - mu*scv;
  }
  __syncthreads();
  for (int i = t; i < 8192; i += 256){
    int c = i & 127;
    float v = z[i]*sc_s[c] + sh_s[c];
    z[i] = fmaxf(v, NEG*v);
  }
  __syncthreads();
  for (int o = t; o < NGRAPH*OUTDIM; o += 256){
    int row = o/OUTDIM, c = o - row*OUTDIM;
    float acc = fc2b[c];
    for (int k = 0; k < 128; k++) acc += z[row*128 + k]*fc2w[k*OUTDIM + c];
    out[o] = acc;
  }
}

extern "C" void kernel_launch(void* const* d_in, const int* in_sizes, int n_in,
                              void* d_out, int out_size, void* d_ws, size_t ws_size,
                              hipStream_t stream){
  (void)in_sizes; (void)n_in; (void)out_size; (void)ws_size;
  const float* x     = (const float*)d_in[0];
  const int*   ei    = (const int*)d_in[1];
  const int*   batch = (const int*)d_in[2];
  const float* cwA[4]; const float* cbA[4]; const float* cwB[4]; const float* cbB[4];
  const float* bng[4]; const float* bnb[4];
  for (int l = 0; l < 4; l++){
    cwA[l] = (const float*)d_in[3 + l*6 + 0];
    cbA[l] = (const float*)d_in[3 + l*6 + 1];
    cwB[l] = (const float*)d_in[3 + l*6 + 2];
    cbB[l] = (const float*)d_in[3 + l*6 + 3];
    bng[l] = (const float*)d_in[3 + l*6 + 4];
    bnb[l] = (const float*)d_in[3 + l*6 + 5];
  }
  const float* fc1w = (const float*)d_in[27];
  const float* fc1b = (const float*)d_in[28];
  const float* fcg  = (const float*)d_in[29];
  const float* fcb  = (const float*)d_in[30];
  const float* fc2w = (const float*)d_in[31];
  const float* fc2b = (const float*)d_in[32];

  char* p = (char*)d_ws;
  auto alloc = [&](size_t bytes)->char* {
    char* r = p; p += (bytes + 511) & ~(size_t)511; return r;
  };
  int* offsets     = (int*)alloc((size_t)(N_NODES+1)*4);
  int* bucketBase  = (int*)alloc((size_t)128*4);
  int* bucketCursor= (int*)alloc((size_t)128*4);
  unsigned* bucketArr = (unsigned*)alloc((size_t)N_EDGES*4);
  int* csr         = (int*)alloc((size_t)N_EDGES*4);
  unsigned short* Wfrag = (unsigned short*)alloc((size_t)8*16384*2);
  unsigned* hn  = (unsigned*)alloc((size_t)PADN*64*4);
  unsigned* spB = (unsigned*)alloc((size_t)PADN*64*4);
  unsigned short* raw = (unsigned short*)alloc((size_t)PADN*128*2);
  float* zz     = (float*)alloc((size_t)(128 + 4*2048 + 8192 + 8192)*4);
  int*   bucketTotal = (int*)zz;
  float* stats  = zz + 128;
  float* pooled = stats + 4*2048;
  float* z1     = pooled + 8192;

  hipMemsetAsync(zz, 0, (size_t)(128 + 4*2048 + 8192)*4, stream);

  convx_kernel<<<(N_NODES*64+255)/256, 256, 0, stream>>>(x, hn);
  convw_kernel<<<8, 256, 0, stream>>>(cwA[0], cwB[0], cwA[1], cwB[1],
                                      cwA[2], cwB[2], cwA[3], cwB[3], Wfrag);

  histA_kernel<<<C_BLOCKS, 1024, 0, stream>>>(ei + N_EDGES, bucketTotal);
  scanB_kernel<<<1, 128, 0, stream>>>(bucketTotal, bucketBase, bucketCursor);
  scatterC_kernel<<<C_BLOCKS, 1024, 0, stream>>>(ei, ei + N_EDGES, bucketCursor, bucketArr);
  buildD_kernel<<<NB, 1024, 0, stream>>>(bucketArr, bucketBase, offsets, csr);

  const int NT32 = PADN/32;   // 1564
  for (int l = 0; l < 4; l++){
    aggregate_kernel<<<12500, 256, 0, stream>>>(hn, offsets, csr, spB);
    mlp_kernel<<<NT32, 256, 0, stream>>>(spB,
          Wfrag + (size_t)(2*l)*16384, Wfrag + (size_t)(2*l+1)*16384,
          cbA[l], cbB[l], raw, stats + l*2048);
    if (l < 3)
      normalize_kernel<<<2048, 256, 0, stream>>>((const unsigned*)raw, hn,
            stats + l*2048, bng[l], bnb[l]);
  }

  pool_kernel<<<NGRAPH*8, 128, 0, stream>>>(raw, batch, stats + 3*2048, bng[3], bnb[3], pooled);
  fc1_kernel<<<NGRAPH, 128, 0, stream>>>(pooled, batch, fc1w, fc1b, z1);
  head2_kernel<<<1, 256, 0, stream>>>(z1, fcg, fcb, fc2w, fc2b, (float*)d_out);
}

// Round 12
// 370.790 us; speedup vs baseline: 1.0028x; 1.0028x over previous
//
#include <hip/hip_runtime.h>

#define N_NODES 50000
#define N_EDGES 800000
#define NGRAPH 64
#define OUTDIM 10
#define NEG 0.1f
#define BN_EPS 1e-5f
#define PADN 50048      // N rounded up to 64
#define NB 98           // coarse buckets (dst >> 9)
#define BK_SHIFT 9
#define BK_NODES 512
#define C_EPB 4096
#define C_BLOCKS 196
#define D_CAP 12288

typedef __attribute__((ext_vector_type(8))) _Float16 f16x8;
typedef __attribute__((ext_vector_type(4))) float f32x4;
typedef __attribute__((ext_vector_type(4))) unsigned u32x4;

// f16 helpers
static __device__ __forceinline__ float h2lo(unsigned u){
  return (float)__builtin_bit_cast(_Float16, (unsigned short)(u & 0xFFFFu));
}
static __device__ __forceinline__ float h2hi(unsigned u){
  return (float)__builtin_bit_cast(_Float16, (unsigned short)(u >> 16));
}
static __device__ __forceinline__ unsigned pack2h(float a, float b){
  unsigned short lo = __builtin_bit_cast(unsigned short, (_Float16)a);
  unsigned short hi = __builtin_bit_cast(unsigned short, (_Float16)b);
  return (((unsigned)hi) << 16) | lo;
}
static __device__ __forceinline__ unsigned short f2h(float a){
  return __builtin_bit_cast(unsigned short, (_Float16)a);
}
static __device__ __forceinline__ float h2f(unsigned short s){
  return (float)__builtin_bit_cast(_Float16, s);
}

__device__ __forceinline__ int lb_search(const int* a, int n, int v){
  int lo = 0, hi = n;
  while (lo < hi){ int m = (lo+hi)>>1; if (a[m] < v) lo = m+1; else hi = m; }
  return lo;
}

// ================= CSR build: 2-level counting sort =================
__global__ __launch_bounds__(1024) void histA_kernel(const int* __restrict__ dst,
      int* __restrict__ bucketTotal){
  __shared__ int cnt[NB];
  const int t = threadIdx.x;
  if (t < NB) cnt[t] = 0;
  __syncthreads();
  const int base = blockIdx.x*C_EPB;
  const int nE = min(C_EPB, N_EDGES - base);
  for (int i = t; i < nE; i += 1024)
    atomicAdd(&cnt[dst[base+i] >> BK_SHIFT], 1);
  __syncthreads();
  if (t < NB) atomicAdd(&bucketTotal[t], cnt[t]);
}

__global__ __launch_bounds__(128) void scanB_kernel(const int* __restrict__ bucketTotal,
      int* __restrict__ bucketBase, int* __restrict__ bucketCursor){
  __shared__ int s[128];
  const int t = threadIdx.x;
  int v = (t < NB) ? bucketTotal[t] : 0;
  s[t] = v; __syncthreads();
  for (int off = 1; off < 128; off <<= 1){
    int a = (t >= off) ? s[t-off] : 0;
    __syncthreads();
    s[t] += a;
    __syncthreads();
  }
  int excl = s[t] - v;
  if (t < NB){ bucketBase[t] = excl; bucketCursor[t] = excl; }
  if (t == NB-1) bucketBase[NB] = s[t];
}

__global__ __launch_bounds__(1024) void scatterC_kernel(const int* __restrict__ src,
      const int* __restrict__ dst, int* __restrict__ bucketCursor,
      unsigned* __restrict__ bucketArr){
  __shared__ int cnt[NB];
  __shared__ int gbase[NB];
  __shared__ int scan_s[128];
  __shared__ unsigned sorted[C_EPB];
  const int t = threadIdx.x;
  if (t < NB) cnt[t] = 0;
  __syncthreads();
  const int ebase = blockIdx.x*C_EPB;
  const int nE = min(C_EPB, N_EDGES - ebase);
  unsigned pk[4]; int bk[4], rk[4];
  #pragma unroll
  for (int i = 0; i < 4; i++){
    int idx = t + i*1024;
    bk[i] = -1;
    if (idx < nE){
      int d = dst[ebase+idx];
      int s0 = src[ebase+idx];
      bk[i] = d >> BK_SHIFT;
      pk[i] = (unsigned)s0 | ((unsigned)(d & (BK_NODES-1)) << 16);
      rk[i] = atomicAdd(&cnt[bk[i]], 1);
    }
  }
  __syncthreads();
  int myc = 0;
  if (t < 128){ myc = (t < NB) ? cnt[t] : 0; scan_s[t] = myc; }
  __syncthreads();
  for (int off = 1; off < 128; off <<= 1){
    int a = 0;
    if (t < 128 && t >= off) a = scan_s[t-off];
    __syncthreads();
    if (t < 128) scan_s[t] += a;
    __syncthreads();
  }
  if (t < NB){
    cnt[t] = scan_s[t] - myc;
    gbase[t] = atomicAdd(&bucketCursor[t], myc);
  }
  __syncthreads();
  #pragma unroll
  for (int i = 0; i < 4; i++)
    if (bk[i] >= 0) sorted[cnt[bk[i]] + rk[i]] = pk[i];
  __syncthreads();
  for (int i = t; i < nE; i += 1024){
    int lo = 0, hi = NB;
    while (hi - lo > 1){ int m = (lo+hi)>>1; if (cnt[m] <= i) lo = m; else hi = m; }
    bucketArr[gbase[lo] + (i - cnt[lo])] = sorted[i];
  }
}

__global__ __launch_bounds__(1024) void buildD_kernel(const unsigned* __restrict__ bucketArr,
      const int* __restrict__ bucketBase, int* __restrict__ offsets, int* __restrict__ col){
  __shared__ int cnt[BK_NODES];
  __shared__ unsigned sorted[D_CAP];
  const int b = blockIdx.x, t = threadIdx.x;
  const int bB = bucketBase[b];
  int nE = bucketBase[b+1] - bB;
  if (nE > D_CAP) nE = D_CAP;
  if (t < BK_NODES) cnt[t] = 0;
  __syncthreads();
  unsigned pk[12]; int rk[12];
  #pragma unroll
  for (int i = 0; i < 12; i++){
    int idx = t + i*1024;
    rk[i] = -1;
    if (idx < nE){
      unsigned e = bucketArr[bB + idx];
      pk[i] = e;
      rk[i] = atomicAdd(&cnt[e >> 16], 1);
    }
  }
  __syncthreads();
  int myc = (t < BK_NODES) ? cnt[t] : 0;
  for (int off = 1; off < BK_NODES; off <<= 1){
    int a = 0;
    if (t < BK_NODES && t >= off) a = cnt[t-off];
    __syncthreads();
    if (t < BK_NODES) cnt[t] += a;
    __syncthreads();
  }
  if (t < BK_NODES){
    int excl = cnt[t] - myc;
    int node = b*BK_NODES + t;
    if (node < N_NODES) offsets[node] = bB + excl;
    cnt[t] = excl;
  }
  if (b == NB-1 && t == 0) offsets[N_NODES] = bucketBase[NB];
  __syncthreads();
  #pragma unroll
  for (int i = 0; i < 12; i++)
    if (rk[i] >= 0) sorted[cnt[pk[i] >> 16] + rk[i]] = pk[i] & 0xFFFFu;
  __syncthreads();
  for (int i = t; i < nE; i += 1024) col[bB + i] = (int)sorted[i];
}

// ---------------- x (fp32) -> f16-pair plane ----------------
__global__ __launch_bounds__(256) void convx_kernel(const float* __restrict__ x, unsigned* __restrict__ hn){
  int i = blockIdx.x*256 + threadIdx.x;
  if (i < N_NODES*64){
    float2 v = ((const float2*)x)[i];
    hn[i] = pack2h(v.x, v.y);
  }
}

// ---------------- weight prep: MFMA-fragment-ordered f16 plane ----------------
__global__ __launch_bounds__(256) void convw_kernel(
    const float* __restrict__ w0, const float* __restrict__ w1,
    const float* __restrict__ w2, const float* __restrict__ w3,
    const float* __restrict__ w4, const float* __restrict__ w5,
    const float* __restrict__ w6, const float* __restrict__ w7,
    unsigned short* __restrict__ Wfrag){
  const float* W;
  switch(blockIdx.x){
    case 0: W=w0; break; case 1: W=w1; break; case 2: W=w2; break; case 3: W=w3; break;
    case 4: W=w4; break; case 5: W=w5; break; case 6: W=w6; break; default: W=w7; break;
  }
  unsigned short* o = Wfrag + (size_t)blockIdx.x*16384;
  for (int i = 0; i < 8; i++){
    int f = threadIdx.x*8 + i;
    int l = f & 63, ct = (f>>6) & 7, kb = f>>9;
    __align__(16) unsigned short hh[8];
    #pragma unroll
    for (int j = 0; j < 8; j++){
      int k = kb*32 + (l>>4)*8 + j;
      int n = ct*16 + (l&15);
      hh[j] = f2h(W[(size_t)k*128 + n]);
    }
    *(uint4*)(o + (size_t)f*8) = *(const uint4*)hh;
  }
}

// ---------------- GIN aggregation: f16-pair gather-sum, 16 deep (R8) + nt store -------
__global__ __launch_bounds__(256) void aggregate_kernel(const unsigned* __restrict__ hn,
        const int* __restrict__ offsets, const int* __restrict__ col,
        unsigned* __restrict__ outA){
  int v = (blockIdx.x*256 + threadIdx.x) >> 6;
  int lane = threadIdx.x & 63;
  if (v >= N_NODES) return;
  int s = __builtin_amdgcn_readfirstlane(offsets[v]);
  int e = __builtin_amdgcn_readfirstlane(offsets[v+1]);
  unsigned u = hn[(size_t)v*64 + lane];
  float ax = h2lo(u), ay = h2hi(u);
  int j = s;
  for (; j + 16 <= e; j += 16){                // 16 gathers in flight
    unsigned g[16];
    #pragma unroll
    for (int i = 0; i < 16; i++) g[i] = hn[(size_t)col[j+i]*64 + lane];
    float sx0 = 0.f, sx1 = 0.f, sy0 = 0.f, sy1 = 0.f;
    #pragma unroll
    for (int i = 0; i < 16; i += 2){
      sx0 += h2lo(g[i]);   sy0 += h2hi(g[i]);
      sx1 += h2lo(g[i+1]); sy1 += h2hi(g[i+1]);
    }
    ax += sx0 + sx1; ay += sy0 + sy1;
  }
  for (; j + 4 <= e; j += 4){
    int c0 = col[j], c1 = col[j+1], c2 = col[j+2], c3 = col[j+3];
    unsigned g0 = hn[(size_t)c0*64 + lane];
    unsigned g1 = hn[(size_t)c1*64 + lane];
    unsigned g2 = hn[(size_t)c2*64 + lane];
    unsigned g3 = hn[(size_t)c3*64 + lane];
    ax += (h2lo(g0)+h2lo(g1)) + (h2lo(g2)+h2lo(g3));
    ay += (h2hi(g0)+h2hi(g1)) + (h2hi(g2)+h2hi(g3));
  }
  for (; j < e; j++){
    unsigned gv = hn[(size_t)col[j]*64 + lane];
    ax += h2lo(gv); ay += h2hi(gv);
  }
  // streaming output: don't let it evict the gather plane from L2
  __builtin_nontemporal_store(pack2h(ax, ay), &outA[(size_t)v*64 + lane]);
}

// ---------------- fused MLP: GEMM1+leaky -> LDS -> barrier -> GEMM2+leaky + stats ----
// 1564 blocks x 256 thr = 4 waves: rg = w&1 (16-row group), ch = w>>1 (64-col half).
__global__ __launch_bounds__(256) void mlp_kernel(const unsigned* __restrict__ Ain,
      const unsigned short* __restrict__ WfA, const unsigned short* __restrict__ WfB,
      const float* __restrict__ biasA, const float* __restrict__ biasB,
      unsigned short* __restrict__ raw, float* __restrict__ stats){
  __shared__ unsigned short mid[32*128];      // 8 KB, XOR-swizzled
  const int tid = threadIdx.x;
  const int w = tid >> 6, l = tid & 63, lr = l & 15, lg = l >> 4;
  const int rg = w & 1, ch = w >> 1;
  const int rowA = blockIdx.x*32 + rg*16 + lr;
  const u32x4* ap = (const u32x4*)(Ain + (size_t)rowA*64);
  const f16x8* wpA = (const f16x8*)WfA;
  const f16x8* wpB = (const f16x8*)WfB;
  f32x4 acc[4];

  // GEMM1: 16 rows x 64 cols (col tiles ch*4 .. +4)
  #pragma unroll
  for (int c = 0; c < 4; c++) acc[c] = (f32x4){0.f,0.f,0.f,0.f};
  #pragma unroll
  for (int kb = 0; kb < 4; kb++){
    u32x4 av = __builtin_nontemporal_load(&ap[kb*4 + lg]);   // single-use stream
    f16x8 a = __builtin_bit_cast(f16x8, av);
    #pragma unroll
    for (int c = 0; c < 4; c++){
      f16x8 wv = wpA[(kb*8 + ch*4 + c)*64 + l];
      acc[c] = __builtin_amdgcn_mfma_f32_16x16x32_f16(a, wv, acc[c], 0, 0, 0);
    }
  }
  #pragma unroll
  for (int c = 0; c < 4; c++){
    int colc = (ch*4 + c)*16 + lr;
    float bv = biasA[colc];
    #pragma unroll
    for (int r = 0; r < 4; r++){
      int row = rg*16 + lg*4 + r;
      float tv = acc[c][r] + bv;
      float o = fmaxf(tv, NEG*tv);
      int off = (row*256 + colc*2) ^ ((row&7)<<4);
      *(unsigned short*)((char*)mid + off) = f2h(o);
    }
  }
  __syncthreads();

  // GEMM2: same 16 rows x 64 cols, K = 128 from mid
  #pragma unroll
  for (int c = 0; c < 4; c++) acc[c] = (f32x4){0.f,0.f,0.f,0.f};
  const int mrow = rg*16 + lr;
  const int mswz = (mrow&7) << 4;
  #pragma unroll
  for (int kb = 0; kb < 4; kb++){
    int boff = (mrow*256 + kb*64 + lg*16) ^ mswz;
    f16x8 a = __builtin_bit_cast(f16x8, *(const u32x4*)((char*)mid + boff));
    #pragma unroll
    for (int c = 0; c < 4; c++){
      f16x8 wv = wpB[(kb*8 + ch*4 + c)*64 + l];
      acc[c] = __builtin_amdgcn_mfma_f32_16x16x32_f16(a, wv, acc[c], 0, 0, 0);
    }
  }
  const int rowO = blockIdx.x*32 + rg*16 + lg*4;
  #pragma unroll
  for (int c = 0; c < 4; c++){
    const int gcol = (ch*4 + c)*16 + lr;
    const float bv = biasB[gcol];
    float s = 0.f, q = 0.f;
    #pragma unroll
    for (int r = 0; r < 4; r++){
      int grow = rowO + r;
      float tv = acc[c][r] + bv;
      float o = fmaxf(tv, NEG*tv);
      if (grow < N_NODES){
        __builtin_nontemporal_store(f2h(o), &raw[(size_t)grow*128 + gcol]);
        s += o; q += o*o;
      }
    }
    s += __shfl_xor(s, 16, 64); s += __shfl_xor(s, 32, 64);
    q += __shfl_xor(q, 16, 64); q += __shfl_xor(q, 32, 64);
    if (lg == 0){
      float* st = stats + (blockIdx.x & 7)*256;
      atomicAdd(&st[gcol], s);
      atomicAdd(&st[128 + gcol], q);
    }
  }
}

// ---------------- BN finalize + normalize + leaky: raw f16 -> hn f16-pair ----------------
__global__ __launch_bounds__(256) void normalize_kernel(const unsigned* __restrict__ raw,
      unsigned* __restrict__ hn, const float* __restrict__ stats,
      const float* __restrict__ g, const float* __restrict__ b){
  __shared__ float sc_s[128], sh_s[128];
  int t = threadIdx.x;
  if (t < 128){
    float su = 0.f, qu = 0.f;
    #pragma unroll
    for (int s8 = 0; s8 < 8; s8++){ su += stats[s8*256 + t]; qu += stats[s8*256 + 128 + t]; }
    float mu = su*(1.f/N_NODES), var = qu*(1.f/N_NODES) - mu*mu;
    float s = g[t]*rsqrtf(var + BN_EPS);
    sc_s[t] = s; sh_s[t] = b[t] - mu*s;
  }
  __syncthreads();
  const int total = N_NODES*64;
  for (int i = blockIdx.x*256 + threadIdx.x; i < total; i += gridDim.x*256){
    unsigned u = __builtin_nontemporal_load(&raw[i]);
    int c0 = (i & 63)*2;
    float v0 = h2lo(u)*sc_s[c0]   + sh_s[c0];
    float v1 = h2hi(u)*sc_s[c0+1] + sh_s[c0+1];
    v0 = fmaxf(v0, NEG*v0); v1 = fmaxf(v1, NEG*v1);
    hn[i] = pack2h(v0, v1);
  }
}

// ---------------- pooling with fused BN+leaky (layer 4) ----------------
__global__ __launch_bounds__(128) void pool_kernel(const unsigned short* __restrict__ raw,
      const int* __restrict__ batch, const float* __restrict__ stats,
      const float* __restrict__ g, const float* __restrict__ b, float* __restrict__ pooled){
  int gi = blockIdx.x >> 3, part = blockIdx.x & 7;
  int c = threadIdx.x;
  float su = 0.f, qu = 0.f;
  #pragma unroll
  for (int s8 = 0; s8 < 8; s8++){ su += stats[s8*256 + c]; qu += stats[s8*256 + 128 + c]; }
  float mu = su*(1.f/N_NODES), var = qu*(1.f/N_NODES) - mu*mu;
  float sc = g[c]*rsqrtf(var+BN_EPS), sh = b[c] - mu*sc;
  int s0 = lb_search(batch, N_NODES, gi), e0 = lb_search(batch, N_NODES, gi+1);
  int len = e0 - s0;
  int a  = s0 + ((len*part) >> 3);
  int b2 = s0 + ((len*(part+1)) >> 3);
  float acc = 0.f;
  for (int r = a; r < b2; r++){
    float t = h2f(raw[(size_t)r*128 + c])*sc + sh;
    acc += fmaxf(t, NEG*t);
  }
  atomicAdd(&pooled[gi*128 + c], acc);
}

// ---------------- head ----------------
__global__ __launch_bounds__(128) void fc1_kernel(const float* __restrict__ pooled,
      const int* __restrict__ batch, const float* __restrict__ fc1w,
      const float* __restrict__ fc1b, float* __restrict__ z1){
  __shared__ float ps[128];
  __shared__ float invs;
  const int gi = blockIdx.x, t = threadIdx.x;
  if (t == 0){
    int s = lb_search(batch, N_NODES, gi), e = lb_search(batch, N_NODES, gi+1);
    invs = 1.f / fmaxf((float)(e - s), 1.f);
  }
  ps[t] = pooled[gi*128 + t];
  __syncthreads();
  float inv = invs;
  float acc = 0.f;
  #pragma unroll 8
  for (int k = 0; k < 128; k++) acc += ps[k]*fc1w[k*128 + t];
  z1[gi*128 + t] = acc*inv + fc1b[t];
}

__global__ __launch_bounds__(256) void head2_kernel(const float* __restrict__ z1,
      const float* __restrict__ g, const float* __restrict__ b,
      const float* __restrict__ fc2w, const float* __restrict__ fc2b,
      float* __restrict__ out){
  __shared__ float z[64*128];
  __shared__ float sc_s[128], sh_s[128];
  const int t = threadIdx.x;
  for (int i = t; i < 8192; i += 256) z[i] = z1[i];
  __syncthreads();
  if (t < 128){
    float s = 0.f, q = 0.f;
    for (int r = 0; r < 64; r++){ float v = z[r*128 + t]; s += v; q += v*v; }
    float mu = s*(1.f/64.f), var = q*(1.f/64.f) - mu*mu;
    float scv = g[t] * rsqrtf(var + BN_EPS);
    sc_s[t] = scv; sh_s[t] = b[t] - mu*scv;
  }
  __syncthreads();
  for (int i = t; i < 8192; i += 256){
    int c = i & 127;
    float v = z[i]*sc_s[c] + sh_s[c];
    z[i] = fmaxf(v, NEG*v);
  }
  __syncthreads();
  for (int o = t; o < NGRAPH*OUTDIM; o += 256){
    int row = o/OUTDIM, c = o - row*OUTDIM;
    float acc = fc2b[c];
    for (int k = 0; k < 128; k++) acc += z[row*128 + k]*fc2w[k*OUTDIM + c];
    out[o] = acc;
  }
}

extern "C" void kernel_launch(void* const* d_in, const int* in_sizes, int n_in,
                              void* d_out, int out_size, void* d_ws, size_t ws_size,
                              hipStream_t stream){
  (void)in_sizes; (void)n_in; (void)out_size; (void)ws_size;
  const float* x     = (const float*)d_in[0];
  const int*   ei    = (const int*)d_in[1];
  const int*   batch = (const int*)d_in[2];
  const float* cwA[4]; const float* cbA[4]; const float* cwB[4]; const float* cbB[4];
  const float* bng[4]; const float* bnb[4];
  for (int l = 0; l < 4; l++){
    cwA[l] = (const float*)d_in[3 + l*6 + 0];
    cbA[l] = (const float*)d_in[3 + l*6 + 1];
    cwB[l] = (const float*)d_in[3 + l*6 + 2];
    cbB[l] = (const float*)d_in[3 + l*6 + 3];
    bng[l] = (const float*)d_in[3 + l*6 + 4];
    bnb[l] = (const float*)d_in[3 + l*6 + 5];
  }
  const float* fc1w = (const float*)d_in[27];
  const float* fc1b = (const float*)d_in[28];
  const float* fcg  = (const float*)d_in[29];
  const float* fcb  = (const float*)d_in[30];
  const float* fc2w = (const float*)d_in[31];
  const float* fc2b = (const float*)d_in[32];

  char* p = (char*)d_ws;
  auto alloc = [&](size_t bytes)->char* {
    char* r = p; p += (bytes + 511) & ~(size_t)511; return r;
  };
  int* offsets     = (int*)alloc((size_t)(N_NODES+1)*4);
  int* bucketBase  = (int*)alloc((size_t)128*4);
  int* bucketCursor= (int*)alloc((size_t)128*4);
  unsigned* bucketArr = (unsigned*)alloc((size_t)N_EDGES*4);
  int* csr         = (int*)alloc((size_t)N_EDGES*4);
  unsigned short* Wfrag = (unsigned short*)alloc((size_t)8*16384*2);
  unsigned* hn  = (unsigned*)alloc((size_t)PADN*64*4);
  unsigned* spB = (unsigned*)alloc((size_t)PADN*64*4);
  unsigned short* raw = (unsigned short*)alloc((size_t)PADN*128*2);
  float* zz     = (float*)alloc((size_t)(128 + 4*2048 + 8192 + 8192)*4);
  int*   bucketTotal = (int*)zz;
  float* stats  = zz + 128;
  float* pooled = stats + 4*2048;
  float* z1     = pooled + 8192;

  hipMemsetAsync(zz, 0, (size_t)(128 + 4*2048 + 8192)*4, stream);

  convx_kernel<<<(N_NODES*64+255)/256, 256, 0, stream>>>(x, hn);
  convw_kernel<<<8, 256, 0, stream>>>(cwA[0], cwB[0], cwA[1], cwB[1],
                                      cwA[2], cwB[2], cwA[3], cwB[3], Wfrag);

  histA_kernel<<<C_BLOCKS, 1024, 0, stream>>>(ei + N_EDGES, bucketTotal);
  scanB_kernel<<<1, 128, 0, stream>>>(bucketTotal, bucketBase, bucketCursor);
  scatterC_kernel<<<C_BLOCKS, 1024, 0, stream>>>(ei, ei + N_EDGES, bucketCursor, bucketArr);
  buildD_kernel<<<NB, 1024, 0, stream>>>(bucketArr, bucketBase, offsets, csr);

  const int NT32 = PADN/32;   // 1564
  for (int l = 0; l < 4; l++){
    aggregate_kernel<<<12500, 256, 0, stream>>>(hn, offsets, csr, spB);
    mlp_kernel<<<NT32, 256, 0, stream>>>(spB,
          Wfrag + (size_t)(2*l)*16384, Wfrag + (size_t)(2*l+1)*16384,
          cbA[l], cbB[l], raw, stats + l*2048);
    if (l < 3)
      normalize_kernel<<<2048, 256, 0, stream>>>((const unsigned*)raw, hn,
            stats + l*2048, bng[l], bnb[l]);
  }

  pool_kernel<<<NGRAPH*8, 128, 0, stream>>>(raw, batch, stats + 3*2048, bng[3], bnb[3], pooled);
  fc1_kernel<<<NGRAPH, 128, 0, stream>>>(pooled, batch, fc1w, fc1b, z1);
  head2_kernel<<<1, 256, 0, stream>>>(z1, fcg, fcb, fc2w, fc2b, (float*)d_out);
}

// Round 13
// 317.756 us; speedup vs baseline: 1.1701x; 1.1669x over previous
//
#include <hip/hip_runtime.h>

#define N_NODES 50000
#define N_EDGES 800000
#define NGRAPH 64
#define OUTDIM 10
#define NEG 0.1f
#define BN_EPS 1e-5f
#define PADN 50048      // N rounded up to 64
#define NB 98           // coarse buckets (dst >> 9)
#define BK_SHIFT 9
#define BK_NODES 512
#define C_EPB 4096
#define C_BLOCKS 196
#define D_CAP 12288
#define PPARTS 64       // pool parts per graph

typedef __attribute__((ext_vector_type(8))) _Float16 f16x8;
typedef __attribute__((ext_vector_type(4))) float f32x4;
typedef __attribute__((ext_vector_type(4))) unsigned u32x4;

// f16 helpers
static __device__ __forceinline__ float h2lo(unsigned u){
  return (float)__builtin_bit_cast(_Float16, (unsigned short)(u & 0xFFFFu));
}
static __device__ __forceinline__ float h2hi(unsigned u){
  return (float)__builtin_bit_cast(_Float16, (unsigned short)(u >> 16));
}
static __device__ __forceinline__ unsigned pack2h(float a, float b){
  unsigned short lo = __builtin_bit_cast(unsigned short, (_Float16)a);
  unsigned short hi = __builtin_bit_cast(unsigned short, (_Float16)b);
  return (((unsigned)hi) << 16) | lo;
}
static __device__ __forceinline__ unsigned short f2h(float a){
  return __builtin_bit_cast(unsigned short, (_Float16)a);
}
static __device__ __forceinline__ float h2f(unsigned short s){
  return (float)__builtin_bit_cast(_Float16, s);
}

__device__ __forceinline__ int lb_search(const int* a, int n, int v){
  int lo = 0, hi = n;
  while (lo < hi){ int m = (lo+hi)>>1; if (a[m] < v) lo = m+1; else hi = m; }
  return lo;
}

// ================= CSR build: 2-level counting sort =================
__global__ __launch_bounds__(1024) void histA_kernel(const int* __restrict__ dst,
      int* __restrict__ bucketTotal){
  __shared__ int cnt[NB];
  const int t = threadIdx.x;
  if (t < NB) cnt[t] = 0;
  __syncthreads();
  const int base = blockIdx.x*C_EPB;
  const int nE = min(C_EPB, N_EDGES - base);
  for (int i = t; i < nE; i += 1024)
    atomicAdd(&cnt[dst[base+i] >> BK_SHIFT], 1);
  __syncthreads();
  if (t < NB) atomicAdd(&bucketTotal[t], cnt[t]);
}

__global__ __launch_bounds__(128) void scanB_kernel(const int* __restrict__ bucketTotal,
      int* __restrict__ bucketBase, int* __restrict__ bucketCursor){
  __shared__ int s[128];
  const int t = threadIdx.x;
  int v = (t < NB) ? bucketTotal[t] : 0;
  s[t] = v; __syncthreads();
  for (int off = 1; off < 128; off <<= 1){
    int a = (t >= off) ? s[t-off] : 0;
    __syncthreads();
    s[t] += a;
    __syncthreads();
  }
  int excl = s[t] - v;
  if (t < NB){ bucketBase[t] = excl; bucketCursor[t] = excl; }
  if (t == NB-1) bucketBase[NB] = s[t];
}

__global__ __launch_bounds__(1024) void scatterC_kernel(const int* __restrict__ src,
      const int* __restrict__ dst, int* __restrict__ bucketCursor,
      unsigned* __restrict__ bucketArr){
  __shared__ int cnt[NB];
  __shared__ int gbase[NB];
  __shared__ int scan_s[128];
  __shared__ unsigned sorted[C_EPB];
  const int t = threadIdx.x;
  if (t < NB) cnt[t] = 0;
  __syncthreads();
  const int ebase = blockIdx.x*C_EPB;
  const int nE = min(C_EPB, N_EDGES - ebase);
  unsigned pk[4]; int bk[4], rk[4];
  #pragma unroll
  for (int i = 0; i < 4; i++){
    int idx = t + i*1024;
    bk[i] = -1;
    if (idx < nE){
      int d = dst[ebase+idx];
      int s0 = src[ebase+idx];
      bk[i] = d >> BK_SHIFT;
      pk[i] = (unsigned)s0 | ((unsigned)(d & (BK_NODES-1)) << 16);
      rk[i] = atomicAdd(&cnt[bk[i]], 1);
    }
  }
  __syncthreads();
  int myc = 0;
  if (t < 128){ myc = (t < NB) ? cnt[t] : 0; scan_s[t] = myc; }
  __syncthreads();
  for (int off = 1; off < 128; off <<= 1){
    int a = 0;
    if (t < 128 && t >= off) a = scan_s[t-off];
    __syncthreads();
    if (t < 128) scan_s[t] += a;
    __syncthreads();
  }
  if (t < NB){
    cnt[t] = scan_s[t] - myc;
    gbase[t] = atomicAdd(&bucketCursor[t], myc);
  }
  __syncthreads();
  #pragma unroll
  for (int i = 0; i < 4; i++)
    if (bk[i] >= 0) sorted[cnt[bk[i]] + rk[i]] = pk[i];
  __syncthreads();
  for (int i = t; i < nE; i += 1024){
    int lo = 0, hi = NB;
    while (hi - lo > 1){ int m = (lo+hi)>>1; if (cnt[m] <= i) lo = m; else hi = m; }
    bucketArr[gbase[lo] + (i - cnt[lo])] = sorted[i];
  }
}

__global__ __launch_bounds__(1024) void buildD_kernel(const unsigned* __restrict__ bucketArr,
      const int* __restrict__ bucketBase, int* __restrict__ offsets, int* __restrict__ col){
  __shared__ int cnt[BK_NODES];
  __shared__ unsigned sorted[D_CAP];
  const int b = blockIdx.x, t = threadIdx.x;
  const int bB = bucketBase[b];
  int nE = bucketBase[b+1] - bB;
  if (nE > D_CAP) nE = D_CAP;
  if (t < BK_NODES) cnt[t] = 0;
  __syncthreads();
  unsigned pk[12]; int rk[12];
  #pragma unroll
  for (int i = 0; i < 12; i++){
    int idx = t + i*1024;
    rk[i] = -1;
    if (idx < nE){
      unsigned e = bucketArr[bB + idx];
      pk[i] = e;
      rk[i] = atomicAdd(&cnt[e >> 16], 1);
    }
  }
  __syncthreads();
  int myc = (t < BK_NODES) ? cnt[t] : 0;
  for (int off = 1; off < BK_NODES; off <<= 1){
    int a = 0;
    if (t < BK_NODES && t >= off) a = cnt[t-off];
    __syncthreads();
    if (t < BK_NODES) cnt[t] += a;
    __syncthreads();
  }
  if (t < BK_NODES){
    int excl = cnt[t] - myc;
    int node = b*BK_NODES + t;
    if (node < N_NODES) offsets[node] = bB + excl;
    cnt[t] = excl;
  }
  if (b == NB-1 && t == 0) offsets[N_NODES] = bucketBase[NB];
  __syncthreads();
  #pragma unroll
  for (int i = 0; i < 12; i++)
    if (rk[i] >= 0) sorted[cnt[pk[i] >> 16] + rk[i]] = pk[i] & 0xFFFFu;
  __syncthreads();
  for (int i = t; i < nE; i += 1024) col[bB + i] = (int)sorted[i];
}

// ---------------- graph boundaries (once) ----------------
__global__ __launch_bounds__(128) void bounds_kernel(const int* __restrict__ batch,
      int* __restrict__ gstart){
  int g = threadIdx.x;
  if (g <= NGRAPH) gstart[g] = lb_search(batch, N_NODES, g);
}

// ---------------- x (fp32) -> f16-pair plane ----------------
__global__ __launch_bounds__(256) void convx_kernel(const float* __restrict__ x, unsigned* __restrict__ hn){
  int i = blockIdx.x*256 + threadIdx.x;
  if (i < N_NODES*64){
    float2 v = ((const float2*)x)[i];
    hn[i] = pack2h(v.x, v.y);
  }
}

// ---------------- weight prep: MFMA-fragment-ordered f16 plane ----------------
__global__ __launch_bounds__(256) void convw_kernel(
    const float* __restrict__ w0, const float* __restrict__ w1,
    const float* __restrict__ w2, const float* __restrict__ w3,
    const float* __restrict__ w4, const float* __restrict__ w5,
    const float* __restrict__ w6, const float* __restrict__ w7,
    unsigned short* __restrict__ Wfrag){
  const float* W;
  switch(blockIdx.x){
    case 0: W=w0; break; case 1: W=w1; break; case 2: W=w2; break; case 3: W=w3; break;
    case 4: W=w4; break; case 5: W=w5; break; case 6: W=w6; break; default: W=w7; break;
  }
  unsigned short* o = Wfrag + (size_t)blockIdx.x*16384;
  for (int i = 0; i < 8; i++){
    int f = threadIdx.x*8 + i;
    int l = f & 63, ct = (f>>6) & 7, kb = f>>9;
    __align__(16) unsigned short hh[8];
    #pragma unroll
    for (int j = 0; j < 8; j++){
      int k = kb*32 + (l>>4)*8 + j;
      int n = ct*16 + (l&15);
      hh[j] = f2h(W[(size_t)k*128 + n]);
    }
    *(uint4*)(o + (size_t)f*8) = *(const uint4*)hh;
  }
}

// ---------------- GIN aggregation: f16-pair gather-sum, 16 deep (R8) ----------------
__global__ __launch_bounds__(256) void aggregate_kernel(const unsigned* __restrict__ hn,
        const int* __restrict__ offsets, const int* __restrict__ col,
        unsigned* __restrict__ outA){
  int v = (blockIdx.x*256 + threadIdx.x) >> 6;
  int lane = threadIdx.x & 63;
  if (v >= N_NODES) return;
  int s = __builtin_amdgcn_readfirstlane(offsets[v]);
  int e = __builtin_amdgcn_readfirstlane(offsets[v+1]);
  unsigned u = hn[(size_t)v*64 + lane];
  float ax = h2lo(u), ay = h2hi(u);
  int j = s;
  for (; j + 16 <= e; j += 16){                // 16 gathers in flight
    unsigned g[16];
    #pragma unroll
    for (int i = 0; i < 16; i++) g[i] = hn[(size_t)col[j+i]*64 + lane];
    float sx0 = 0.f, sx1 = 0.f, sy0 = 0.f, sy1 = 0.f;
    #pragma unroll
    for (int i = 0; i < 16; i += 2){
      sx0 += h2lo(g[i]);   sy0 += h2hi(g[i]);
      sx1 += h2lo(g[i+1]); sy1 += h2hi(g[i+1]);
    }
    ax += sx0 + sx1; ay += sy0 + sy1;
  }
  for (; j + 4 <= e; j += 4){
    int c0 = col[j], c1 = col[j+1], c2 = col[j+2], c3 = col[j+3];
    unsigned g0 = hn[(size_t)c0*64 + lane];
    unsigned g1 = hn[(size_t)c1*64 + lane];
    unsigned g2 = hn[(size_t)c2*64 + lane];
    unsigned g3 = hn[(size_t)c3*64 + lane];
    ax += (h2lo(g0)+h2lo(g1)) + (h2lo(g2)+h2lo(g3));
    ay += (h2hi(g0)+h2hi(g1)) + (h2hi(g2)+h2hi(g3));
  }
  for (; j < e; j++){
    unsigned gv = hn[(size_t)col[j]*64 + lane];
    ax += h2lo(gv); ay += h2hi(gv);
  }
  outA[(size_t)v*64 + lane] = pack2h(ax, ay);
}

// ---------------- fused MLP: GEMM1+leaky -> LDS -> barrier -> GEMM2+leaky + stats ----
// 1564 blocks x 256 thr = 4 waves: rg = w&1 (16-row group), ch = w>>1 (64-col half).
__global__ __launch_bounds__(256) void mlp_kernel(const unsigned* __restrict__ Ain,
      const unsigned short* __restrict__ WfA, const unsigned short* __restrict__ WfB,
      const float* __restrict__ biasA, const float* __restrict__ biasB,
      unsigned short* __restrict__ raw, float* __restrict__ stats){
  __shared__ unsigned short mid[32*128];      // 8 KB, XOR-swizzled
  const int tid = threadIdx.x;
  const int w = tid >> 6, l = tid & 63, lr = l & 15, lg = l >> 4;
  const int rg = w & 1, ch = w >> 1;
  const int rowA = blockIdx.x*32 + rg*16 + lr;
  const u32x4* ap = (const u32x4*)(Ain + (size_t)rowA*64);
  const f16x8* wpA = (const f16x8*)WfA;
  const f16x8* wpB = (const f16x8*)WfB;
  f32x4 acc[4];

  // GEMM1: 16 rows x 64 cols (col tiles ch*4 .. +4)
  #pragma unroll
  for (int c = 0; c < 4; c++) acc[c] = (f32x4){0.f,0.f,0.f,0.f};
  #pragma unroll
  for (int kb = 0; kb < 4; kb++){
    f16x8 a = __builtin_bit_cast(f16x8, ap[kb*4 + lg]);
    #pragma unroll
    for (int c = 0; c < 4; c++){
      f16x8 wv = wpA[(kb*8 + ch*4 + c)*64 + l];
      acc[c] = __builtin_amdgcn_mfma_f32_16x16x32_f16(a, wv, acc[c], 0, 0, 0);
    }
  }
  #pragma unroll
  for (int c = 0; c < 4; c++){
    int colc = (ch*4 + c)*16 + lr;
    float bv = biasA[colc];
    #pragma unroll
    for (int r = 0; r < 4; r++){
      int row = rg*16 + lg*4 + r;
      float tv = acc[c][r] + bv;
      float o = fmaxf(tv, NEG*tv);
      int off = (row*256 + colc*2) ^ ((row&7)<<4);
      *(unsigned short*)((char*)mid + off) = f2h(o);
    }
  }
  __syncthreads();

  // GEMM2: same 16 rows x 64 cols, K = 128 from mid
  #pragma unroll
  for (int c = 0; c < 4; c++) acc[c] = (f32x4){0.f,0.f,0.f,0.f};
  const int mrow = rg*16 + lr;
  const int mswz = (mrow&7) << 4;
  #pragma unroll
  for (int kb = 0; kb < 4; kb++){
    int boff = (mrow*256 + kb*64 + lg*16) ^ mswz;
    f16x8 a = __builtin_bit_cast(f16x8, *(const u32x4*)((char*)mid + boff));
    #pragma unroll
    for (int c = 0; c < 4; c++){
      f16x8 wv = wpB[(kb*8 + ch*4 + c)*64 + l];
      acc[c] = __builtin_amdgcn_mfma_f32_16x16x32_f16(a, wv, acc[c], 0, 0, 0);
    }
  }
  const int rowO = blockIdx.x*32 + rg*16 + lg*4;
  #pragma unroll
  for (int c = 0; c < 4; c++){
    const int gcol = (ch*4 + c)*16 + lr;
    const float bv = biasB[gcol];
    float s = 0.f, q = 0.f;
    #pragma unroll
    for (int r = 0; r < 4; r++){
      int grow = rowO + r;
      float tv = acc[c][r] + bv;
      float o = fmaxf(tv, NEG*tv);
      if (grow < N_NODES){
        raw[(size_t)grow*128 + gcol] = f2h(o);
        s += o; q += o*o;
      }
    }
    s += __shfl_xor(s, 16, 64); s += __shfl_xor(s, 32, 64);
    q += __shfl_xor(q, 16, 64); q += __shfl_xor(q, 32, 64);
    if (lg == 0){
      float* st = stats + (blockIdx.x & 7)*256;
      atomicAdd(&st[gcol], s);
      atomicAdd(&st[128 + gcol], q);
    }
  }
}

// ---------------- BN finalize + normalize + leaky: raw f16 -> hn f16-pair ----------------
__global__ __launch_bounds__(256) void normalize_kernel(const unsigned* __restrict__ raw,
      unsigned* __restrict__ hn, const float* __restrict__ stats,
      const float* __restrict__ g, const float* __restrict__ b){
  __shared__ float sc_s[128], sh_s[128];
  int t = threadIdx.x;
  if (t < 128){
    float su = 0.f, qu = 0.f;
    #pragma unroll
    for (int s8 = 0; s8 < 8; s8++){ su += stats[s8*256 + t]; qu += stats[s8*256 + 128 + t]; }
    float mu = su*(1.f/N_NODES), var = qu*(1.f/N_NODES) - mu*mu;
    float s = g[t]*rsqrtf(var + BN_EPS);
    sc_s[t] = s; sh_s[t] = b[t] - mu*s;
  }
  __syncthreads();
  const int total = N_NODES*64;
  for (int i = blockIdx.x*256 + threadIdx.x; i < total; i += gridDim.x*256){
    unsigned u = raw[i];
    int c0 = (i & 63)*2;
    float v0 = h2lo(u)*sc_s[c0]   + sh_s[c0];
    float v1 = h2hi(u)*sc_s[c0+1] + sh_s[c0+1];
    v0 = fmaxf(v0, NEG*v0); v1 = fmaxf(v1, NEG*v1);
    hn[i] = pack2h(v0, v1);
  }
}

// ---------------- pooling with fused BN+leaky (layer 4), 64 parts/graph ----------------
__global__ __launch_bounds__(128) void pool_kernel(const unsigned short* __restrict__ raw,
      const int* __restrict__ gstart, const float* __restrict__ stats,
      const float* __restrict__ g, const float* __restrict__ b, float* __restrict__ pooled){
  int gi = blockIdx.x >> 6, part = blockIdx.x & (PPARTS-1);
  int c = threadIdx.x;
  float su = 0.f, qu = 0.f;
  #pragma unroll
  for (int s8 = 0; s8 < 8; s8++){ su += stats[s8*256 + c]; qu += stats[s8*256 + 128 + c]; }
  float mu = su*(1.f/N_NODES), var = qu*(1.f/N_NODES) - mu*mu;
  float sc = g[c]*rsqrtf(var+BN_EPS), sh = b[c] - mu*sc;
  int s0 = gstart[gi], e0 = gstart[gi+1];
  int len = e0 - s0;
  int a  = s0 + (len*part)/PPARTS;
  int b2 = s0 + (len*(part+1))/PPARTS;
  float acc = 0.f;
  for (int r = a; r < b2; r++){
    float t = h2f(raw[(size_t)r*128 + c])*sc + sh;
    acc += fmaxf(t, NEG*t);
  }
  if (a < b2) atomicAdd(&pooled[gi*128 + c], acc);
}

// ---------------- head ----------------
__global__ __launch_bounds__(128) void fc1_kernel(const float* __restrict__ pooled,
      const int* __restrict__ gstart, const float* __restrict__ fc1w,
      const float* __restrict__ fc1b, float* __restrict__ z1){
  __shared__ float ps[128];
  const int gi = blockIdx.x, t = threadIdx.x;
  float inv = 1.f / fmaxf((float)(gstart[gi+1] - gstart[gi]), 1.f);
  ps[t] = pooled[gi*128 + t];
  __syncthreads();
  float acc = 0.f;
  #pragma unroll 8
  for (int k = 0; k < 128; k++) acc += ps[k]*fc1w[k*128 + t];
  z1[gi*128 + t] = acc*inv + fc1b[t];
}

__global__ __launch_bounds__(256) void head2_kernel(const float* __restrict__ z1,
      const float* __restrict__ g, const float* __restrict__ b,
      const float* __restrict__ fc2w, const float* __restrict__ fc2b,
      float* __restrict__ out){
  __shared__ float z[64*128];
  __shared__ float sc_s[128], sh_s[128];
  const int t = threadIdx.x;
  for (int i = t; i < 8192; i += 256) z[i] = z1[i];
  __syncthreads();
  if (t < 128){
    float s = 0.f, q = 0.f;
    for (int r = 0; r < 64; r++){ float v = z[r*128 + t]; s += v; q += v*v; }
    float mu = s*(1.f/64.f), var = q*(1.f/64.f) - mu*mu;
    float scv = g[t] * rsqrtf(var + BN_EPS);
    sc_s[t] = scv; sh_s[t] = b[t] - mu*scv;
  }
  __syncthreads();
  for (int i = t; i < 8192; i += 256){
    int c = i & 127;
    float v = z[i]*sc_s[c] + sh_s[c];
    z[i] = fmaxf(v, NEG*v);
  }
  __syncthreads();
  for (int o = t; o < NGRAPH*OUTDIM; o += 256){
    int row = o/OUTDIM, c = o - row*OUTDIM;
    float acc = fc2b[c];
    for (int k = 0; k < 128; k++) acc += z[row*128 + k]*fc2w[k*OUTDIM + c];
    out[o] = acc;
  }
}

extern "C" void kernel_launch(void* const* d_in, const int* in_sizes, int n_in,
                              void* d_out, int out_size, void* d_ws, size_t ws_size,
                              hipStream_t stream){
  (void)in_sizes; (void)n_in; (void)out_size; (void)ws_size;
  const float* x     = (const float*)d_in[0];
  const int*   ei    = (const int*)d_in[1];
  const int*   batch = (const int*)d_in[2];
  const float* cwA[4]; const float* cbA[4]; const float* cwB[4]; const float* cbB[4];
  const float* bng[4]; const float* bnb[4];
  for (int l = 0; l < 4; l++){
    cwA[l] = (const float*)d_in[3 + l*6 + 0];
    cbA[l] = (const float*)d_in[3 + l*6 + 1];
    cwB[l] = (const float*)d_in[3 + l*6 + 2];
    cbB[l] = (const float*)d_in[3 + l*6 + 3];
    bng[l] = (const float*)d_in[3 + l*6 + 4];
    bnb[l] = (const float*)d_in[3 + l*6 + 5];
  }
  const float* fc1w = (const float*)d_in[27];
  const float* fc1b = (const float*)d_in[28];
  const float* fcg  = (const float*)d_in[29];
  const float* fcb  = (const float*)d_in[30];
  const float* fc2w = (const float*)d_in[31];
  const float* fc2b = (const float*)d_in[32];

  char* p = (char*)d_ws;
  auto alloc = [&](size_t bytes)->char* {
    char* r = p; p += (bytes + 511) & ~(size_t)511; return r;
  };
  int* offsets     = (int*)alloc((size_t)(N_NODES+1)*4);
  int* bucketBase  = (int*)alloc((size_t)128*4);
  int* bucketCursor= (int*)alloc((size_t)128*4);
  int* gstart      = (int*)alloc((size_t)(NGRAPH+1)*4);
  unsigned* bucketArr = (unsigned*)alloc((size_t)N_EDGES*4);
  int* csr         = (int*)alloc((size_t)N_EDGES*4);
  unsigned short* Wfrag = (unsigned short*)alloc((size_t)8*16384*2);
  unsigned* hn  = (unsigned*)alloc((size_t)PADN*64*4);
  unsigned* spB = (unsigned*)alloc((size_t)PADN*64*4);
  unsigned short* raw = (unsigned short*)alloc((size_t)PADN*128*2);
  float* zz     = (float*)alloc((size_t)(128 + 4*2048 + 8192 + 8192)*4);
  int*   bucketTotal = (int*)zz;
  float* stats  = zz + 128;
  float* pooled = stats + 4*2048;
  float* z1     = pooled + 8192;

  hipMemsetAsync(zz, 0, (size_t)(128 + 4*2048 + 8192)*4, stream);

  convx_kernel<<<(N_NODES*64+255)/256, 256, 0, stream>>>(x, hn);
  convw_kernel<<<8, 256, 0, stream>>>(cwA[0], cwB[0], cwA[1], cwB[1],
                                      cwA[2], cwB[2], cwA[3], cwB[3], Wfrag);
  bounds_kernel<<<1, 128, 0, stream>>>(batch, gstart);

  histA_kernel<<<C_BLOCKS, 1024, 0, stream>>>(ei + N_EDGES, bucketTotal);
  scanB_kernel<<<1, 128, 0, stream>>>(bucketTotal, bucketBase, bucketCursor);
  scatterC_kernel<<<C_BLOCKS, 1024, 0, stream>>>(ei, ei + N_EDGES, bucketCursor, bucketArr);
  buildD_kernel<<<NB, 1024, 0, stream>>>(bucketArr, bucketBase, offsets, csr);

  const int NT32 = PADN/32;   // 1564
  for (int l = 0; l < 4; l++){
    aggregate_kernel<<<12500, 256, 0, stream>>>(hn, offsets, csr, spB);
    mlp_kernel<<<NT32, 256, 0, stream>>>(spB,
          Wfrag + (size_t)(2*l)*16384, Wfrag + (size_t)(2*l+1)*16384,
          cbA[l], cbB[l], raw, stats + l*2048);
    if (l < 3)
      normalize_kernel<<<2048, 256, 0, stream>>>((const unsigned*)raw, hn,
            stats + l*2048, bng[l], bnb[l]);
  }

  pool_kernel<<<NGRAPH*PPARTS, 128, 0, stream>>>(raw, gstart, stats + 3*2048,
        bng[3], bnb[3], pooled);
  fc1_kernel<<<NGRAPH, 128, 0, stream>>>(pooled, gstart, fc1w, fc1b, z1);
  head2_kernel<<<1, 256, 0, stream>>>(z1, fcg, fcb, fc2w, fc2b, (float*)d_out);
}

// Round 14
// 317.553 us; speedup vs baseline: 1.1709x; 1.0006x over previous
//
#include <hip/hip_runtime.h>

#define N_NODES 50000
#define N_EDGES 800000
#define NGRAPH 64
#define OUTDIM 10
#define NEG 0.1f
#define BN_EPS 1e-5f
#define PADN 50048      // N rounded up to 64
#define NB 98           // coarse buckets (dst >> 9)
#define BK_SHIFT 9
#define BK_NODES 512
#define C_EPB 4096
#define C_BLOCKS 196
#define D_CAP 12288
#define PPARTS 64       // pool parts per graph

typedef __attribute__((ext_vector_type(8))) _Float16 f16x8;
typedef __attribute__((ext_vector_type(4))) float f32x4;
typedef __attribute__((ext_vector_type(4))) unsigned u32x4;

// f16 helpers
static __device__ __forceinline__ float h2lo(unsigned u){
  return (float)__builtin_bit_cast(_Float16, (unsigned short)(u & 0xFFFFu));
}
static __device__ __forceinline__ float h2hi(unsigned u){
  return (float)__builtin_bit_cast(_Float16, (unsigned short)(u >> 16));
}
static __device__ __forceinline__ unsigned pack2h(float a, float b){
  unsigned short lo = __builtin_bit_cast(unsigned short, (_Float16)a);
  unsigned short hi = __builtin_bit_cast(unsigned short, (_Float16)b);
  return (((unsigned)hi) << 16) | lo;
}
static __device__ __forceinline__ unsigned short f2h(float a){
  return __builtin_bit_cast(unsigned short, (_Float16)a);
}
static __device__ __forceinline__ float h2f(unsigned short s){
  return (float)__builtin_bit_cast(_Float16, s);
}

__device__ __forceinline__ int lb_search(const int* a, int n, int v){
  int lo = 0, hi = n;
  while (lo < hi){ int m = (lo+hi)>>1; if (a[m] < v) lo = m+1; else hi = m; }
  return lo;
}

// ================= CSR build: 2-level counting sort =================
__global__ __launch_bounds__(1024) void histA_kernel(const int* __restrict__ dst,
      int* __restrict__ bucketTotal){
  __shared__ int cnt[NB];
  const int t = threadIdx.x;
  if (t < NB) cnt[t] = 0;
  __syncthreads();
  const int base = blockIdx.x*C_EPB;
  const int nE = min(C_EPB, N_EDGES - base);
  for (int i = t; i < nE; i += 1024)
    atomicAdd(&cnt[dst[base+i] >> BK_SHIFT], 1);
  __syncthreads();
  if (t < NB) atomicAdd(&bucketTotal[t], cnt[t]);
}

__global__ __launch_bounds__(128) void scanB_kernel(const int* __restrict__ bucketTotal,
      int* __restrict__ bucketBase, int* __restrict__ bucketCursor){
  __shared__ int s[128];
  const int t = threadIdx.x;
  int v = (t < NB) ? bucketTotal[t] : 0;
  s[t] = v; __syncthreads();
  for (int off = 1; off < 128; off <<= 1){
    int a = (t >= off) ? s[t-off] : 0;
    __syncthreads();
    s[t] += a;
    __syncthreads();
  }
  int excl = s[t] - v;
  if (t < NB){ bucketBase[t] = excl; bucketCursor[t] = excl; }
  if (t == NB-1) bucketBase[NB] = s[t];
}

__global__ __launch_bounds__(1024) void scatterC_kernel(const int* __restrict__ src,
      const int* __restrict__ dst, int* __restrict__ bucketCursor,
      unsigned* __restrict__ bucketArr){
  __shared__ int cnt[NB];
  __shared__ int gbase[NB];
  __shared__ int scan_s[128];
  __shared__ unsigned sorted[C_EPB];
  const int t = threadIdx.x;
  if (t < NB) cnt[t] = 0;
  __syncthreads();
  const int ebase = blockIdx.x*C_EPB;
  const int nE = min(C_EPB, N_EDGES - ebase);
  unsigned pk[4]; int bk[4], rk[4];
  #pragma unroll
  for (int i = 0; i < 4; i++){
    int idx = t + i*1024;
    bk[i] = -1;
    if (idx < nE){
      int d = dst[ebase+idx];
      int s0 = src[ebase+idx];
      bk[i] = d >> BK_SHIFT;
      pk[i] = (unsigned)s0 | ((unsigned)(d & (BK_NODES-1)) << 16);
      rk[i] = atomicAdd(&cnt[bk[i]], 1);
    }
  }
  __syncthreads();
  int myc = 0;
  if (t < 128){ myc = (t < NB) ? cnt[t] : 0; scan_s[t] = myc; }
  __syncthreads();
  for (int off = 1; off < 128; off <<= 1){
    int a = 0;
    if (t < 128 && t >= off) a = scan_s[t-off];
    __syncthreads();
    if (t < 128) scan_s[t] += a;
    __syncthreads();
  }
  if (t < NB){
    cnt[t] = scan_s[t] - myc;
    gbase[t] = atomicAdd(&bucketCursor[t], myc);
  }
  __syncthreads();
  #pragma unroll
  for (int i = 0; i < 4; i++)
    if (bk[i] >= 0) sorted[cnt[bk[i]] + rk[i]] = pk[i];
  __syncthreads();
  for (int i = t; i < nE; i += 1024){
    int lo = 0, hi = NB;
    while (hi - lo > 1){ int m = (lo+hi)>>1; if (cnt[m] <= i) lo = m; else hi = m; }
    bucketArr[gbase[lo] + (i - cnt[lo])] = sorted[i];
  }
}

__global__ __launch_bounds__(1024) void buildD_kernel(const unsigned* __restrict__ bucketArr,
      const int* __restrict__ bucketBase, int* __restrict__ offsets, int* __restrict__ col){
  __shared__ int cnt[BK_NODES];
  __shared__ unsigned sorted[D_CAP];
  const int b = blockIdx.x, t = threadIdx.x;
  const int bB = bucketBase[b];
  int nE = bucketBase[b+1] - bB;
  if (nE > D_CAP) nE = D_CAP;
  if (t < BK_NODES) cnt[t] = 0;
  __syncthreads();
  unsigned pk[12]; int rk[12];
  #pragma unroll
  for (int i = 0; i < 12; i++){
    int idx = t + i*1024;
    rk[i] = -1;
    if (idx < nE){
      unsigned e = bucketArr[bB + idx];
      pk[i] = e;
      rk[i] = atomicAdd(&cnt[e >> 16], 1);
    }
  }
  __syncthreads();
  int myc = (t < BK_NODES) ? cnt[t] : 0;
  for (int off = 1; off < BK_NODES; off <<= 1){
    int a = 0;
    if (t < BK_NODES && t >= off) a = cnt[t-off];
    __syncthreads();
    if (t < BK_NODES) cnt[t] += a;
    __syncthreads();
  }
  if (t < BK_NODES){
    int excl = cnt[t] - myc;
    int node = b*BK_NODES + t;
    if (node < N_NODES) offsets[node] = bB + excl;
    cnt[t] = excl;
  }
  if (b == NB-1 && t == 0) offsets[N_NODES] = bucketBase[NB];
  __syncthreads();
  #pragma unroll
  for (int i = 0; i < 12; i++)
    if (rk[i] >= 0) sorted[cnt[pk[i] >> 16] + rk[i]] = pk[i] & 0xFFFFu;
  __syncthreads();
  for (int i = t; i < nE; i += 1024) col[bB + i] = (int)sorted[i];
}

// ---------------- graph boundaries (once) ----------------
__global__ __launch_bounds__(128) void bounds_kernel(const int* __restrict__ batch,
      int* __restrict__ gstart){
  int g = threadIdx.x;
  if (g <= NGRAPH) gstart[g] = lb_search(batch, N_NODES, g);
}

// ---------------- x (fp32) -> f16-pair plane ----------------
__global__ __launch_bounds__(256) void convx_kernel(const float* __restrict__ x, unsigned* __restrict__ hn){
  int i = blockIdx.x*256 + threadIdx.x;
  if (i < N_NODES*64){
    float2 v = ((const float2*)x)[i];
    hn[i] = pack2h(v.x, v.y);
  }
}

// ---------------- weight prep: MFMA-fragment-ordered f16 plane ----------------
__global__ __launch_bounds__(256) void convw_kernel(
    const float* __restrict__ w0, const float* __restrict__ w1,
    const float* __restrict__ w2, const float* __restrict__ w3,
    const float* __restrict__ w4, const float* __restrict__ w5,
    const float* __restrict__ w6, const float* __restrict__ w7,
    unsigned short* __restrict__ Wfrag){
  const float* W;
  switch(blockIdx.x){
    case 0: W=w0; break; case 1: W=w1; break; case 2: W=w2; break; case 3: W=w3; break;
    case 4: W=w4; break; case 5: W=w5; break; case 6: W=w6; break; default: W=w7; break;
  }
  unsigned short* o = Wfrag + (size_t)blockIdx.x*16384;
  for (int i = 0; i < 8; i++){
    int f = threadIdx.x*8 + i;
    int l = f & 63, ct = (f>>6) & 7, kb = f>>9;
    __align__(16) unsigned short hh[8];
    #pragma unroll
    for (int j = 0; j < 8; j++){
      int k = kb*32 + (l>>4)*8 + j;
      int n = ct*16 + (l&15);
      hh[j] = f2h(W[(size_t)k*128 + n]);
    }
    *(uint4*)(o + (size_t)f*8) = *(const uint4*)hh;
  }
}

// ---------------- GIN aggregation: f16-pair gather-sum, 16 deep, 32-bit addressing ----
__global__ __launch_bounds__(256) void aggregate_kernel(const unsigned* __restrict__ hn,
        const int* __restrict__ offsets, const int* __restrict__ col,
        unsigned* __restrict__ outA){
  int v = (blockIdx.x*256 + threadIdx.x) >> 6;
  unsigned lane = threadIdx.x & 63;
  if (v >= N_NODES) return;
  int s = __builtin_amdgcn_readfirstlane(offsets[v]);
  int e = __builtin_amdgcn_readfirstlane(offsets[v+1]);
  const unsigned selfOff = ((unsigned)v << 6) | lane;   // u32 element index, < 3.2M
  unsigned u = hn[selfOff];
  float ax = h2lo(u), ay = h2hi(u);
  int j = s;
  for (; j + 16 <= e; j += 16){                // 16 gathers in flight
    unsigned g[16];
    #pragma unroll
    for (int i = 0; i < 16; i++)
      g[i] = hn[(((unsigned)col[j+i]) << 6) | lane];
    float sx0 = 0.f, sx1 = 0.f, sy0 = 0.f, sy1 = 0.f;
    #pragma unroll
    for (int i = 0; i < 16; i += 2){
      sx0 += h2lo(g[i]);   sy0 += h2hi(g[i]);
      sx1 += h2lo(g[i+1]); sy1 += h2hi(g[i+1]);
    }
    ax += sx0 + sx1; ay += sy0 + sy1;
  }
  for (; j + 4 <= e; j += 4){
    unsigned g0 = hn[(((unsigned)col[j])   << 6) | lane];
    unsigned g1 = hn[(((unsigned)col[j+1]) << 6) | lane];
    unsigned g2 = hn[(((unsigned)col[j+2]) << 6) | lane];
    unsigned g3 = hn[(((unsigned)col[j+3]) << 6) | lane];
    ax += (h2lo(g0)+h2lo(g1)) + (h2lo(g2)+h2lo(g3));
    ay += (h2hi(g0)+h2hi(g1)) + (h2hi(g2)+h2hi(g3));
  }
  for (; j < e; j++){
    unsigned gv = hn[(((unsigned)col[j]) << 6) | lane];
    ax += h2lo(gv); ay += h2hi(gv);
  }
  outA[selfOff] = pack2h(ax, ay);
}

// ---------------- fused MLP: GEMM1+leaky -> LDS -> barrier -> GEMM2+leaky + stats ----
// 1564 blocks x 256 thr = 4 waves: rg = w&1 (16-row group), ch = w>>1 (64-col half).
__global__ __launch_bounds__(256) void mlp_kernel(const unsigned* __restrict__ Ain,
      const unsigned short* __restrict__ WfA, const unsigned short* __restrict__ WfB,
      const float* __restrict__ biasA, const float* __restrict__ biasB,
      unsigned short* __restrict__ raw, float* __restrict__ stats){
  __shared__ unsigned short mid[32*128];      // 8 KB, XOR-swizzled
  const int tid = threadIdx.x;
  const int w = tid >> 6, l = tid & 63, lr = l & 15, lg = l >> 4;
  const int rg = w & 1, ch = w >> 1;
  const int rowA = blockIdx.x*32 + rg*16 + lr;
  const u32x4* ap = (const u32x4*)(Ain + (size_t)rowA*64);
  const f16x8* wpA = (const f16x8*)WfA;
  const f16x8* wpB = (const f16x8*)WfB;
  f32x4 acc[4];

  // GEMM1: 16 rows x 64 cols (col tiles ch*4 .. +4)
  #pragma unroll
  for (int c = 0; c < 4; c++) acc[c] = (f32x4){0.f,0.f,0.f,0.f};
  #pragma unroll
  for (int kb = 0; kb < 4; kb++){
    f16x8 a = __builtin_bit_cast(f16x8, ap[kb*4 + lg]);
    #pragma unroll
    for (int c = 0; c < 4; c++){
      f16x8 wv = wpA[(kb*8 + ch*4 + c)*64 + l];
      acc[c] = __builtin_amdgcn_mfma_f32_16x16x32_f16(a, wv, acc[c], 0, 0, 0);
    }
  }
  #pragma unroll
  for (int c = 0; c < 4; c++){
    int colc = (ch*4 + c)*16 + lr;
    float bv = biasA[colc];
    #pragma unroll
    for (int r = 0; r < 4; r++){
      int row = rg*16 + lg*4 + r;
      float tv = acc[c][r] + bv;
      float o = fmaxf(tv, NEG*tv);
      int off = (row*256 + colc*2) ^ ((row&7)<<4);
      *(unsigned short*)((char*)mid + off) = f2h(o);
    }
  }
  __syncthreads();

  // GEMM2: same 16 rows x 64 cols, K = 128 from mid
  #pragma unroll
  for (int c = 0; c < 4; c++) acc[c] = (f32x4){0.f,0.f,0.f,0.f};
  const int mrow = rg*16 + lr;
  const int mswz = (mrow&7) << 4;
  #pragma unroll
  for (int kb = 0; kb < 4; kb++){
    int boff = (mrow*256 + kb*64 + lg*16) ^ mswz;
    f16x8 a = __builtin_bit_cast(f16x8, *(const u32x4*)((char*)mid + boff));
    #pragma unroll
    for (int c = 0; c < 4; c++){
      f16x8 wv = wpB[(kb*8 + ch*4 + c)*64 + l];
      acc[c] = __builtin_amdgcn_mfma_f32_16x16x32_f16(a, wv, acc[c], 0, 0, 0);
    }
  }
  const int rowO = blockIdx.x*32 + rg*16 + lg*4;
  #pragma unroll
  for (int c = 0; c < 4; c++){
    const int gcol = (ch*4 + c)*16 + lr;
    const float bv = biasB[gcol];
    float s = 0.f, q = 0.f;
    #pragma unroll
    for (int r = 0; r < 4; r++){
      int grow = rowO + r;
      float tv = acc[c][r] + bv;
      float o = fmaxf(tv, NEG*tv);
      if (grow < N_NODES){
        raw[(size_t)grow*128 + gcol] = f2h(o);
        s += o; q += o*o;
      }
    }
    s += __shfl_xor(s, 16, 64); s += __shfl_xor(s, 32, 64);
    q += __shfl_xor(q, 16, 64); q += __shfl_xor(q, 32, 64);
    if (lg == 0){
      float* st = stats + (blockIdx.x & 7)*256;
      atomicAdd(&st[gcol], s);
      atomicAdd(&st[128 + gcol], q);
    }
  }
}

// ---------------- BN finalize + normalize + leaky: raw f16 -> hn f16-pair ----------------
__global__ __launch_bounds__(256) void normalize_kernel(const unsigned* __restrict__ raw,
      unsigned* __restrict__ hn, const float* __restrict__ stats,
      const float* __restrict__ g, const float* __restrict__ b){
  __shared__ float sc_s[128], sh_s[128];
  int t = threadIdx.x;
  if (t < 128){
    float su = 0.f, qu = 0.f;
    #pragma unroll
    for (int s8 = 0; s8 < 8; s8++){ su += stats[s8*256 + t]; qu += stats[s8*256 + 128 + t]; }
    float mu = su*(1.f/N_NODES), var = qu*(1.f/N_NODES) - mu*mu;
    float s = g[t]*rsqrtf(var + BN_EPS);
    sc_s[t] = s; sh_s[t] = b[t] - mu*s;
  }
  __syncthreads();
  const int total = N_NODES*64;
  for (int i = blockIdx.x*256 + threadIdx.x; i < total; i += gridDim.x*256){
    unsigned u = raw[i];
    int c0 = (i & 63)*2;
    float v0 = h2lo(u)*sc_s[c0]   + sh_s[c0];
    float v1 = h2hi(u)*sc_s[c0+1] + sh_s[c0+1];
    v0 = fmaxf(v0, NEG*v0); v1 = fmaxf(v1, NEG*v1);
    hn[i] = pack2h(v0, v1);
  }
}

// ---------------- pooling with fused BN+leaky (layer 4), 64 parts/graph ----------------
__global__ __launch_bounds__(128) void pool_kernel(const unsigned short* __restrict__ raw,
      const int* __restrict__ gstart, const float* __restrict__ stats,
      const float* __restrict__ g, const float* __restrict__ b, float* __restrict__ pooled){
  int gi = blockIdx.x >> 6, part = blockIdx.x & (PPARTS-1);
  int c = threadIdx.x;
  float su = 0.f, qu = 0.f;
  #pragma unroll
  for (int s8 = 0; s8 < 8; s8++){ su += stats[s8*256 + c]; qu += stats[s8*256 + 128 + c]; }
  float mu = su*(1.f/N_NODES), var = qu*(1.f/N_NODES) - mu*mu;
  float sc = g[c]*rsqrtf(var+BN_EPS), sh = b[c] - mu*sc;
  int s0 = gstart[gi], e0 = gstart[gi+1];
  int len = e0 - s0;
  int a  = s0 + (len*part)/PPARTS;
  int b2 = s0 + (len*(part+1))/PPARTS;
  float acc = 0.f;
  for (int r = a; r < b2; r++){
    float t = h2f(raw[(size_t)r*128 + c])*sc + sh;
    acc += fmaxf(t, NEG*t);
  }
  if (a < b2) atomicAdd(&pooled[gi*128 + c], acc);
}

// ---------------- head ----------------
__global__ __launch_bounds__(128) void fc1_kernel(const float* __restrict__ pooled,
      const int* __restrict__ gstart, const float* __restrict__ fc1w,
      const float* __restrict__ fc1b, float* __restrict__ z1){
  __shared__ float ps[128];
  const int gi = blockIdx.x, t = threadIdx.x;
  float inv = 1.f / fmaxf((float)(gstart[gi+1] - gstart[gi]), 1.f);
  ps[t] = pooled[gi*128 + t];
  __syncthreads();
  float acc = 0.f;
  #pragma unroll 8
  for (int k = 0; k < 128; k++) acc += ps[k]*fc1w[k*128 + t];
  z1[gi*128 + t] = acc*inv + fc1b[t];
}

__global__ __launch_bounds__(256) void head2_kernel(const float* __restrict__ z1,
      const float* __restrict__ g, const float* __restrict__ b,
      const float* __restrict__ fc2w, const float* __restrict__ fc2b,
      float* __restrict__ out){
  __shared__ float z[64*128];
  __shared__ float sc_s[128], sh_s[128];
  const int t = threadIdx.x;
  for (int i = t; i < 8192; i += 256) z[i] = z1[i];
  __syncthreads();
  if (t < 128){
    float s = 0.f, q = 0.f;
    for (int r = 0; r < 64; r++){ float v = z[r*128 + t]; s += v; q += v*v; }
    float mu = s*(1.f/64.f), var = q*(1.f/64.f) - mu*mu;
    float scv = g[t] * rsqrtf(var + BN_EPS);
    sc_s[t] = scv; sh_s[t] = b[t] - mu*scv;
  }
  __syncthreads();
  for (int i = t; i < 8192; i += 256){
    int c = i & 127;
    float v = z[i]*sc_s[c] + sh_s[c];
    z[i] = fmaxf(v, NEG*v);
  }
  __syncthreads();
  for (int o = t; o < NGRAPH*OUTDIM; o += 256){
    int row = o/OUTDIM, c = o - row*OUTDIM;
    float acc = fc2b[c];
    for (int k = 0; k < 128; k++) acc += z[row*128 + k]*fc2w[k*OUTDIM + c];
    out[o] = acc;
  }
}

extern "C" void kernel_launch(void* const* d_in, const int* in_sizes, int n_in,
                              void* d_out, int out_size, void* d_ws, size_t ws_size,
                              hipStream_t stream){
  (void)in_sizes; (void)n_in; (void)out_size; (void)ws_size;
  const float* x     = (const float*)d_in[0];
  const int*   ei    = (const int*)d_in[1];
  const int*   batch = (const int*)d_in[2];
  const float* cwA[4]; const float* cbA[4]; const float* cwB[4]; const float* cbB[4];
  const float* bng[4]; const float* bnb[4];
  for (int l = 0; l < 4; l++){
    cwA[l] = (const float*)d_in[3 + l*6 + 0];
    cbA[l] = (const float*)d_in[3 + l*6 + 1];
    cwB[l] = (const float*)d_in[3 + l*6 + 2];
    cbB[l] = (const float*)d_in[3 + l*6 + 3];
    bng[l] = (const float*)d_in[3 + l*6 + 4];
    bnb[l] = (const float*)d_in[3 + l*6 + 5];
  }
  const float* fc1w = (const float*)d_in[27];
  const float* fc1b = (const float*)d_in[28];
  const float* fcg  = (const float*)d_in[29];
  const float* fcb  = (const float*)d_in[30];
  const float* fc2w = (const float*)d_in[31];
  const float* fc2b = (const float*)d_in[32];

  char* p = (char*)d_ws;
  auto alloc = [&](size_t bytes)->char* {
    char* r = p; p += (bytes + 511) & ~(size_t)511; return r;
  };
  int* offsets     = (int*)alloc((size_t)(N_NODES+1)*4);
  int* bucketBase  = (int*)alloc((size_t)128*4);
  int* bucketCursor= (int*)alloc((size_t)128*4);
  int* gstart      = (int*)alloc((size_t)(NGRAPH+1)*4);
  unsigned* bucketArr = (unsigned*)alloc((size_t)N_EDGES*4);
  int* csr         = (int*)alloc((size_t)N_EDGES*4);
  unsigned short* Wfrag = (unsigned short*)alloc((size_t)8*16384*2);
  unsigned* hn  = (unsigned*)alloc((size_t)PADN*64*4);
  unsigned* spB = (unsigned*)alloc((size_t)PADN*64*4);
  unsigned short* raw = (unsigned short*)alloc((size_t)PADN*128*2);
  float* zz     = (float*)alloc((size_t)(128 + 4*2048 + 8192 + 8192)*4);
  int*   bucketTotal = (int*)zz;
  float* stats  = zz + 128;
  float* pooled = stats + 4*2048;
  float* z1     = pooled + 8192;

  hipMemsetAsync(zz, 0, (size_t)(128 + 4*2048 + 8192)*4, stream);

  convx_kernel<<<(N_NODES*64+255)/256, 256, 0, stream>>>(x, hn);
  convw_kernel<<<8, 256, 0, stream>>>(cwA[0], cwB[0], cwA[1], cwB[1],
                                      cwA[2], cwB[2], cwA[3], cwB[3], Wfrag);
  bounds_kernel<<<1, 128, 0, stream>>>(batch, gstart);

  histA_kernel<<<C_BLOCKS, 1024, 0, stream>>>(ei + N_EDGES, bucketTotal);
  scanB_kernel<<<1, 128, 0, stream>>>(bucketTotal, bucketBase, bucketCursor);
  scatterC_kernel<<<C_BLOCKS, 1024, 0, stream>>>(ei, ei + N_EDGES, bucketCursor, bucketArr);
  buildD_kernel<<<NB, 1024, 0, stream>>>(bucketArr, bucketBase, offsets, csr);

  const int NT32 = PADN/32;   // 1564
  for (int l = 0; l < 4; l++){
    aggregate_kernel<<<12500, 256, 0, stream>>>(hn, offsets, csr, spB);
    mlp_kernel<<<NT32, 256, 0, stream>>>(spB,
          Wfrag + (size_t)(2*l)*16384, Wfrag + (size_t)(2*l+1)*16384,
          cbA[l], cbB[l], raw, stats + l*2048);
    if (l < 3)
      normalize_kernel<<<2048, 256, 0, stream>>>((const unsigned*)raw, hn,
            stats + l*2048, bng[l], bnb[l]);
  }

  pool_kernel<<<NGRAPH*PPARTS, 128, 0, stream>>>(raw, gstart, stats + 3*2048,
        bng[3], bnb[3], pooled);
  fc1_kernel<<<NGRAPH, 128, 0, stream>>>(pooled, gstart, fc1w, fc1b, z1);
  head2_kernel<<<1, 256, 0, stream>>>(z1, fcg, fcb, fc2w, fc2b, (float*)d_out);
}